// Round 9
// baseline (5686.439 us; speedup 1.0000x reference)
//
#include <hip/hip_runtime.h>
#include <hip/hip_fp16.h>
#include <hip/hip_bf16.h>

#define B_ 16
#define N_ 64
#define T_ 32
#define D_ 512
#define H_ 256
#define K_ 13
#define S_ 2048
#define G4_ 1024

typedef float f32x4 __attribute__((ext_vector_type(4)));
typedef short s16x8 __attribute__((ext_vector_type(8)));
typedef int   i32x4 __attribute__((ext_vector_type(4)));

#define INVQ 2.0505324e-5f   /* 1/(384*127) */

// barrier with LDS-only drain: do NOT wait vmcnt (global loads/stores stay in flight)
#define BAR() do { \
  asm volatile("s_waitcnt lgkmcnt(0)" ::: "memory"); \
  __builtin_amdgcn_s_barrier(); \
  __builtin_amdgcn_sched_barrier(0); \
} while (0)

__device__ __forceinline__ float sigm(float x){ return 1.0f/(1.0f+__expf(-x)); }
__device__ __forceinline__ float tanh_fast(float x){ return 1.0f - 2.0f/(1.0f+__expf(2.0f*x)); }

// ---------- prefix sums over segment lengths ----------
__global__ void k_prep(const int* __restrict__ length, int* __restrict__ cum, int* __restrict__ doc){
  const int b = threadIdx.x >> 6, n = threadIdx.x & 63;
  const int v = length[b*N_ + n];
  int x = v;
  #pragma unroll
  for (int d = 1; d < 64; d <<= 1){
    int y = __shfl_up(x, d);
    if (n >= d) x += y;
  }
  cum[b*N_ + n] = x - v;          // exclusive
  if (n == 63) doc[b] = x;        // doc_len
}

// ---------- cast weights: w_ih -> bf16 [2048][512]; w_hh -> i8 [dir][1024][256] ----------
__global__ __launch_bounds__(256) void k_cast(const float* __restrict__ wf, const float* __restrict__ wb,
                       const float* __restrict__ hf, const float* __restrict__ hb,
                       ushort* __restrict__ wih, signed char* __restrict__ whh8){
  const int i = blockIdx.x*256 + threadIdx.x;
  if (i < 2*G4_*D_){
    const int dir = i / (G4_*D_); const int r = i % (G4_*D_);
    const float v = dir ? wb[r] : wf[r];
    ((__hip_bfloat16*)wih)[i] = __float2bfloat16(v);
  } else {
    const int j2 = i - 2*G4_*D_;
    if (j2 < 2*G4_*H_){
      const int dir = j2 >> 18; const int r = j2 & 262143;
      const float v = (dir ? hb : hf)[r];
      int q = (int)rintf(v * 384.0f);
      whh8[j2] = (signed char)min(127, max(-127, q));
    }
  }
}

// ---------- scatter source map + packed tags ----------
__global__ __launch_bounds__(256) void k_srcmap(const int* __restrict__ length, const int* __restrict__ cum,
                         const int* __restrict__ tags, int* __restrict__ src, int* __restrict__ ntag){
  const int i = blockIdx.x*256 + threadIdx.x;            // B*N*T = 32768
  const int b = i >> 11, nt = i & 2047, n = nt >> 5, t = nt & 31;
  if (t < length[b*N_ + n]){
    const int dest = cum[b*N_ + n] + t;
    src[b*S_ + dest] = nt;
    ntag[b*S_ + dest] = tags[i];
  }
}

// ---------- build packed new_x (bf16) + mask output ----------
__global__ __launch_bounds__(256) void k_newx(const float* __restrict__ x, const float* __restrict__ gcn,
                      const int* __restrict__ src, const int* __restrict__ doc,
                      ushort* __restrict__ nx, float* __restrict__ mask_out){
  const int r = blockIdx.x; const int b = r >> 11, s = r & 2047;
  const int L = doc[b];
  const int d = threadIdx.x*2;
  const float2 g2 = *(const float2*)&gcn[((size_t)(b*N_ + (s>>5)))*D_ + d];
  float v0 = g2.x, v1 = g2.y;
  if (s < L){
    const int nt = src[r];
    const float2 x2 = *(const float2*)&x[((size_t)(b*S_ + nt))*D_ + d];
    v0 += x2.x; v1 += x2.y;
  }
  __hip_bfloat16* o = (__hip_bfloat16*)nx + (size_t)r*D_ + d;
  o[0] = __float2bfloat16(v0); o[1] = __float2bfloat16(v1);
  if (threadIdx.x == 0) mask_out[r] = (s < L) ? 1.0f : 0.0f;
}

// ---------- input projection GEMM ----------
// pre layout (REMAPPED for recur): pre[b][s][dir*1024 + u*4 + g]  (f16, bias added)
__global__ __launch_bounds__(256) void k_gemm(const ushort* __restrict__ A, const ushort* __restrict__ Bw,
    const float* __restrict__ bias_f, const float* __restrict__ bias_b,
    const int* __restrict__ doc, __half* __restrict__ pre){
  const int m0 = blockIdx.x*128, n0 = blockIdx.y*128;
  const int b = m0 >> 11, s0 = m0 & 2047;
  if (s0 >= doc[b]) return;
  __shared__ __align__(16) ushort la[128*40];
  __shared__ __align__(16) ushort lb[128*40];
  const int tid = threadIdx.x, lane = tid & 63, w = tid >> 6;
  const int wr = w >> 1, wc = w & 1;
  const int fr = lane & 15, fq = lane >> 4;
  f32x4 acc[4][4] = {};
  const int srow = tid >> 1;
  const int sko  = (tid & 1)*16;
  for (int kt = 0; kt < 16; ++kt){
    const int k0 = kt*32;
    const float4 a0 = *(const float4*)&A[(size_t)(m0+srow)*512 + k0 + sko];
    const float4 a1 = *(const float4*)&A[(size_t)(m0+srow)*512 + k0 + sko + 8];
    const float4 b0 = *(const float4*)&Bw[(size_t)(n0+srow)*512 + k0 + sko];
    const float4 b1 = *(const float4*)&Bw[(size_t)(n0+srow)*512 + k0 + sko + 8];
    *(float4*)&la[srow*40 + sko]     = a0;
    *(float4*)&la[srow*40 + sko + 8] = a1;
    *(float4*)&lb[srow*40 + sko]     = b0;
    *(float4*)&lb[srow*40 + sko + 8] = b1;
    __syncthreads();
    s16x8 af[4], bfr[4];
    #pragma unroll
    for (int mi=0; mi<4; ++mi) af[mi] = *(const s16x8*)&la[(wr*64+mi*16+fr)*40 + fq*8];
    #pragma unroll
    for (int ni=0; ni<4; ++ni) bfr[ni] = *(const s16x8*)&lb[(wc*64+ni*16+fr)*40 + fq*8];
    #pragma unroll
    for (int mi=0; mi<4; ++mi){
      #pragma unroll
      for (int ni=0; ni<4; ++ni){
        acc[mi][ni] = __builtin_amdgcn_mfma_f32_16x16x32_bf16(af[mi], bfr[ni], acc[mi][ni], 0, 0, 0);
      }
    }
    __syncthreads();
  }
  #pragma unroll
  for (int ni=0; ni<4; ++ni){
    const int n = n0 + wc*64 + ni*16 + fr;         // gate-row index: dir*1024 + g*256 + u
    const float bv = (n < 1024) ? bias_f[n] : bias_b[n-1024];
    const int dir = n >> 10, g = (n >> 8) & 3, u = n & 255;
    const int col = dir*1024 + u*4 + g;            // remapped column
    #pragma unroll
    for (int mi=0; mi<4; ++mi){
      const int mb = m0 + wr*64 + mi*16 + fq*4;
      #pragma unroll
      for (int j=0; j<4; ++j)
        pre[(size_t)(mb+j)*2048 + col] = __float2half(acc[mi][ni][j] + bv);
    }
  }
}

// ---------- recurrent LSTM: one block per direction, 1024 threads / 16 waves ----------
// grid = 2 (dir). __launch_bounds__(1024,4) pins 4 waves/SIMD -> VGPR budget 128 (hard).
// Register demand ~104: gates i,f,g weight frags in VGPRs (48), gate-o weights in LDS (64KB).
// Lane's acc element j holds chain (lane>>4)*4+j -> all 4 gates local, no redistribution.
__global__ __launch_bounds__(1024, 4) void k_recur9(
    const signed char* __restrict__ W8,
    const __half* __restrict__ pre, const int* __restrict__ doc,
    __half* __restrict__ outh)
{
  const int dir = blockIdx.x;
  const int tid = threadIdx.x, lane = tid & 63, wv = tid >> 6;   // wv 0..15
  const int fr = lane & 15, fq = lane >> 4;

  __shared__ __align__(16) signed char hq[2][4096];   // [buf][chain*256+unit] i8, swizzled
  __shared__ __align__(16) signed char wo[65536];     // o-gate weights i8, swizzled

  // fill wo: 4096 16-B chunks; chunk c -> unit u=c>>4, k-chunk k16=c&15
  #pragma unroll
  for (int i = 0; i < 4; ++i){
    const int c = tid*4 + i;
    const int u = c >> 4, k16 = c & 15;
    const int dst = (u*256 + k16*16) ^ ((u & 7) << 4);
    *(i32x4*)&wo[dst] = *(const i32x4*)&W8[(size_t)dir*262144 + (size_t)(768 + u)*256 + k16*16];
  }
  // zero both h buffers (h_{-1} = 0)
  ((unsigned*)hq)[tid]        = 0u;
  ((unsigned*)hq)[tid + 1024] = 0u;

  int Lc[4]; int Lblk = 0;
  #pragma unroll
  for (int j = 0; j < 4; ++j) Lc[j] = doc[fq*4 + j];
  #pragma unroll
  for (int b = 0; b < 16; ++b) Lblk = max(Lblk, doc[b]);

  // W_hh i8 B-fragments, gates 0..2 (i,f,g): lane holds W[row=g*256+wv*16+fr][kt*64+fq*16 ..+16]
  i32x4 wfrag[3][4];   // 48 VGPRs
  #pragma unroll
  for (int g = 0; g < 3; ++g){
    const int row = g*256 + wv*16 + fr;
    #pragma unroll
    for (int kt = 0; kt < 4; ++kt)
      wfrag[g][kt] = *(const i32x4*)&W8[(size_t)dir*262144 + (size_t)row*256 + kt*64 + fq*16];
  }

  const int u = wv*16 + fr;          // unit this lane owns in the gate phase
  const int swz = (fr & 7) << 4;     // (u&7)==(fr&7) since wv*16 is 0 mod 8
  float cst[4] = {};                 // c state per chain j
  BAR();

  for (int t = 0; t < Lblk; ++t){
    // issue pre loads first; consumed after the MFMA phase (~1300 cy later)
    uint2 pv[4];
    #pragma unroll
    for (int j = 0; j < 4; ++j){
      const int c = fq*4 + j;
      const int pos = dir ? max(Lc[j]-1-t, 0) : t;
      pv[j] = *(const uint2*)(pre + ((size_t)(c*S_ + pos))*2048 + dir*1024 + u*4);
    }

    const int rbuf = (t+1) & 1, wbuf = t & 1;

    // MFMA: A-frag from hq (chains x K), o-gate B-frag from wo LDS, i/f/g B-frags from VGPR
    i32x4 acc[4] = {};
    #pragma unroll
    for (int kt = 0; kt < 4; ++kt){
      const int haddr = (fr*256 + kt*64 + fq*16) ^ swz;
      const i32x4 af = *(const i32x4*)&hq[rbuf][haddr];
      const int waddr = (u*256 + kt*64 + fq*16) ^ swz;
      const i32x4 of = *(const i32x4*)&wo[waddr];
      acc[0] = __builtin_amdgcn_mfma_i32_16x16x64_i8(af, wfrag[0][kt], acc[0], 0, 0, 0);
      acc[1] = __builtin_amdgcn_mfma_i32_16x16x64_i8(af, wfrag[1][kt], acc[1], 0, 0, 0);
      acc[2] = __builtin_amdgcn_mfma_i32_16x16x64_i8(af, wfrag[2][kt], acc[2], 0, 0, 0);
      acc[3] = __builtin_amdgcn_mfma_i32_16x16x64_i8(af, of,           acc[3], 0, 0, 0);
    }

    // gates: lane's element j = chain fq*4+j, unit u; all 4 gates local
    #pragma unroll
    for (int j = 0; j < 4; ++j){
      const int c = fq*4 + j;
      const __half2* ph = (const __half2*)&pv[j];
      const float2 p01 = __half22float2(ph[0]);
      const float2 p23 = __half22float2(ph[1]);
      const float gi = (float)acc[0][j]*INVQ + p01.x;
      const float gf = (float)acc[1][j]*INVQ + p01.y;
      const float gg = (float)acc[2][j]*INVQ + p23.x;
      const float go = (float)acc[3][j]*INVQ + p23.y;
      const float cc = sigm(gf)*cst[j] + sigm(gi)*tanh_fast(gg);
      cst[j] = cc;
      const float h = sigm(go)*tanh_fast(cc);
      int q8 = (int)rintf(h*127.0f);
      q8 = min(127, max(-127, q8));
      hq[wbuf][(c*256 + u) ^ ((c & 7) << 4)] = (signed char)q8;
      if (t < Lc[j]){
        const int pos = dir ? (Lc[j]-1-t) : t;
        outh[((size_t)(c*S_ + pos))*512 + dir*256 + u] = __float2half(h);
      }
    }
    BAR();
  }
}

// ---------- logits: wave per row (outh is f16) ----------
__global__ __launch_bounds__(256) void k_logits(const __half* __restrict__ outh, const float* __restrict__ mw,
    const float* __restrict__ mb, const int* __restrict__ doc, float* __restrict__ logits){
  const int w = threadIdx.x >> 6, lane = threadIdx.x & 63;
  const int r = blockIdx.x*4 + w;
  const int b = r >> 11, s = r & 2047;
  if (s >= doc[b]){
    if (lane < 13) logits[(size_t)r*13 + lane] = mb[lane];
    return;
  }
  float xv[8];
  #pragma unroll
  for (int m=0; m<8; ++m) xv[m] = __half2float(outh[(size_t)r*512 + lane + m*64]);
  #pragma unroll
  for (int k=0; k<13; ++k){
    float p = 0.f;
    #pragma unroll
    for (int m=0; m<8; ++m) p += xv[m]*mw[k*512 + lane + m*64];
    #pragma unroll
    for (int off=32; off; off>>=1) p += __shfl_down(p, off);
    if (lane == 0) logits[(size_t)r*13 + k] = p + mb[k];
  }
}

// ---------- CRF: one wave per batch; exp-transition matvec form ----------
__global__ void k_crf(const float* __restrict__ logits, const int* __restrict__ ntag,
    const int* __restrict__ doc, const float* __restrict__ trans,
    const float* __restrict__ stt, const float* __restrict__ ent, float* __restrict__ ll){
  const int b = blockIdx.x, lane = threadIdx.x;
  const int L = doc[b];
  const float* lg = logits + (size_t)b*S_*13;
  float et[13];
  #pragma unroll
  for (int i=0; i<13; ++i) et[i] = (lane < 13) ? __expf(trans[i*13 + lane]) : 0.f;
  float alpha = (lane < 13) ? (stt[lane] + lg[lane]) : -1e30f;
  float e_nxt = (L > 1 && lane < 13) ? lg[13 + lane] : 0.f;
  for (int t=1; t<L; ++t){
    const float e = e_nxt;
    if (t+1 < L && lane < 13) e_nxt = lg[(size_t)(t+1)*13 + lane];
    float m = alpha;
    #pragma unroll
    for (int off = 1; off < 16; off <<= 1) m = fmaxf(m, __shfl_xor(m, off));
    const float a = __expf(alpha - m);
    float s = 0.f;
    #pragma unroll
    for (int i=0; i<13; ++i) s += __shfl(a, i) * et[i];
    alpha = m + __logf(s) + e;
  }
  float av = (lane < 13) ? alpha + ent[lane] : -1e30f;
  float m2 = -1e30f;
  #pragma unroll
  for (int i=0; i<13; ++i) m2 = fmaxf(m2, __shfl(av, i));
  float s2 = 0.f;
  #pragma unroll
  for (int i=0; i<13; ++i) s2 += __expf(__shfl(av, i) - m2);
  const float logz = m2 + __logf(s2);
  const int* tg = ntag + (size_t)b*S_;
  float num = 0.f;
  for (int t = lane; t < L; t += 64){
    const int cur = tg[t];
    num += lg[(size_t)t*13 + cur];
    if (t >= 1) num += trans[tg[t-1]*13 + cur];
  }
  #pragma unroll
  for (int off=32; off; off>>=1) num += __shfl_down(num, off);
  if (lane == 0){
    num += stt[tg[0]] + ent[tg[L-1]];
    ll[b] = num - logz;
  }
}

extern "C" void kernel_launch(void* const* d_in, const int* in_sizes, int n_in,
                              void* d_out, int out_size, void* d_ws, size_t ws_size,
                              hipStream_t stream){
  const float* x    = (const float*)d_in[0];
  const float* gcn  = (const float*)d_in[1];
  const int* length = (const int*)d_in[3];
  const int* tags   = (const int*)d_in[4];
  const float* wihf = (const float*)d_in[5];
  const float* whhf = (const float*)d_in[6];
  const float* bf   = (const float*)d_in[7];
  const float* wihb = (const float*)d_in[8];
  const float* whhb = (const float*)d_in[9];
  const float* bb   = (const float*)d_in[10];
  const float* mw   = (const float*)d_in[11];
  const float* mb   = (const float*)d_in[12];
  const float* trans= (const float*)d_in[13];
  const float* stt  = (const float*)d_in[14];
  const float* ent  = (const float*)d_in[15];

  char* ws = (char*)d_ws;
  ushort* nx   = (ushort*)(ws + 0);              // 33,554,432 B  new_x bf16
  __half* pre  = (__half*)(ws + 33554432);       // 134,217,728 B pre-activations f16 (remapped cols)
  __half* outh = (__half*)(ws + 167772160);      // 33,554,432 B  concat h states (f16)
  ushort* wih  = (ushort*)(ws + 234881024);      // 2,097,152 B   w_ih bf16 [2048][512]
  signed char* whh8 = (signed char*)(ws + 236978176); // 524,288 B w_hh i8 [2][1024][256]
  int*    src  = (int*)(ws + 238026752);         // 131,072 B
  int*    ntag = (int*)(ws + 238157824);         // 131,072 B
  int*    cum  = (int*)(ws + 238288896);         // 4,096 B
  int*    doc  = (int*)(ws + 238292992);         // 64 B

  float* logits  = (float*)d_out;                // 425,984 floats
  float* maskout = logits + 425984;              // 32,768 floats
  float* ll      = maskout + 32768;              // 16 floats

  hipLaunchKernelGGL(k_prep,   dim3(1),        dim3(1024), 0, stream, length, cum, doc);
  hipLaunchKernelGGL(k_cast,   dim3(6144),     dim3(256),  0, stream, wihf, wihb, whhf, whhb, wih, whh8);
  hipLaunchKernelGGL(k_srcmap, dim3(128),      dim3(256),  0, stream, length, cum, tags, src, ntag);
  hipLaunchKernelGGL(k_newx,   dim3(32768),    dim3(256),  0, stream, x, gcn, src, doc, nx, maskout);
  hipLaunchKernelGGL(k_gemm,   dim3(256, 16),  dim3(256),  0, stream, nx, wih, bf, bb, doc, pre);
  hipLaunchKernelGGL(k_recur9, dim3(2),        dim3(1024), 0, stream, whh8, pre, doc, outh);
  hipLaunchKernelGGL(k_logits, dim3(8192),     dim3(256),  0, stream, outh, mw, mb, doc, logits);
  hipLaunchKernelGGL(k_crf,    dim3(16),       dim3(64),   0, stream, logits, ntag, doc, trans, stt, ent, ll);
}

// Round 10
// 1799.058 us; speedup vs baseline: 3.1608x; 3.1608x over previous
//
#include <hip/hip_runtime.h>
#include <hip/hip_fp16.h>
#include <hip/hip_bf16.h>

#define B_ 16
#define N_ 64
#define T_ 32
#define D_ 512
#define H_ 256
#define K_ 13
#define S_ 2048
#define G4_ 1024

typedef float f32x4 __attribute__((ext_vector_type(4)));
typedef short s16x8 __attribute__((ext_vector_type(8)));
typedef int   i32x4 __attribute__((ext_vector_type(4)));

#define INVQ 2.0505324e-5f   /* 1/(384*127) */

// barrier with LDS-only drain: do NOT wait vmcnt (global loads/stores stay in flight)
#define BAR() do { \
  asm volatile("s_waitcnt lgkmcnt(0)" ::: "memory"); \
  __builtin_amdgcn_s_barrier(); \
  __builtin_amdgcn_sched_barrier(0); \
} while (0)

__device__ __forceinline__ float sigm(float x){ return 1.0f/(1.0f+__expf(-x)); }
__device__ __forceinline__ float tanh_fast(float x){ return 1.0f - 2.0f/(1.0f+__expf(2.0f*x)); }

// ---------- prefix sums over segment lengths ----------
__global__ void k_prep(const int* __restrict__ length, int* __restrict__ cum, int* __restrict__ doc){
  const int b = threadIdx.x >> 6, n = threadIdx.x & 63;
  const int v = length[b*N_ + n];
  int x = v;
  #pragma unroll
  for (int d = 1; d < 64; d <<= 1){
    int y = __shfl_up(x, d);
    if (n >= d) x += y;
  }
  cum[b*N_ + n] = x - v;          // exclusive
  if (n == 63) doc[b] = x;        // doc_len
}

// ---------- cast weights: w_ih -> bf16 [2048][512]; w_hh -> i8 [dir][1024][256] ----------
__global__ __launch_bounds__(256) void k_cast(const float* __restrict__ wf, const float* __restrict__ wb,
                       const float* __restrict__ hf, const float* __restrict__ hb,
                       ushort* __restrict__ wih, signed char* __restrict__ whh8){
  const int i = blockIdx.x*256 + threadIdx.x;
  if (i < 2*G4_*D_){
    const int dir = i / (G4_*D_); const int r = i % (G4_*D_);
    const float v = dir ? wb[r] : wf[r];
    ((__hip_bfloat16*)wih)[i] = __float2bfloat16(v);
  } else {
    const int j2 = i - 2*G4_*D_;
    if (j2 < 2*G4_*H_){
      const int dir = j2 >> 18; const int r = j2 & 262143;
      const float v = (dir ? hb : hf)[r];
      int q = (int)rintf(v * 384.0f);
      whh8[j2] = (signed char)min(127, max(-127, q));
    }
  }
}

// ---------- scatter source map + packed tags ----------
__global__ __launch_bounds__(256) void k_srcmap(const int* __restrict__ length, const int* __restrict__ cum,
                         const int* __restrict__ tags, int* __restrict__ src, int* __restrict__ ntag){
  const int i = blockIdx.x*256 + threadIdx.x;            // B*N*T = 32768
  const int b = i >> 11, nt = i & 2047, n = nt >> 5, t = nt & 31;
  if (t < length[b*N_ + n]){
    const int dest = cum[b*N_ + n] + t;
    src[b*S_ + dest] = nt;
    ntag[b*S_ + dest] = tags[i];
  }
}

// ---------- build packed new_x (bf16) + mask output ----------
__global__ __launch_bounds__(256) void k_newx(const float* __restrict__ x, const float* __restrict__ gcn,
                      const int* __restrict__ src, const int* __restrict__ doc,
                      ushort* __restrict__ nx, float* __restrict__ mask_out){
  const int r = blockIdx.x; const int b = r >> 11, s = r & 2047;
  const int L = doc[b];
  const int d = threadIdx.x*2;
  const float2 g2 = *(const float2*)&gcn[((size_t)(b*N_ + (s>>5)))*D_ + d];
  float v0 = g2.x, v1 = g2.y;
  if (s < L){
    const int nt = src[r];
    const float2 x2 = *(const float2*)&x[((size_t)(b*S_ + nt))*D_ + d];
    v0 += x2.x; v1 += x2.y;
  }
  __hip_bfloat16* o = (__hip_bfloat16*)nx + (size_t)r*D_ + d;
  o[0] = __float2bfloat16(v0); o[1] = __float2bfloat16(v1);
  if (threadIdx.x == 0) mask_out[r] = (s < L) ? 1.0f : 0.0f;
}

// ---------- input projection GEMM ----------
// pre layout (REMAPPED for recur): pre[b][s][dir*1024 + u*4 + g]  (f16, bias added)
__global__ __launch_bounds__(256) void k_gemm(const ushort* __restrict__ A, const ushort* __restrict__ Bw,
    const float* __restrict__ bias_f, const float* __restrict__ bias_b,
    const int* __restrict__ doc, __half* __restrict__ pre){
  const int m0 = blockIdx.x*128, n0 = blockIdx.y*128;
  const int b = m0 >> 11, s0 = m0 & 2047;
  if (s0 >= doc[b]) return;
  __shared__ __align__(16) ushort la[128*40];
  __shared__ __align__(16) ushort lb[128*40];
  const int tid = threadIdx.x, lane = tid & 63, w = tid >> 6;
  const int wr = w >> 1, wc = w & 1;
  const int fr = lane & 15, fq = lane >> 4;
  f32x4 acc[4][4] = {};
  const int srow = tid >> 1;
  const int sko  = (tid & 1)*16;
  for (int kt = 0; kt < 16; ++kt){
    const int k0 = kt*32;
    const float4 a0 = *(const float4*)&A[(size_t)(m0+srow)*512 + k0 + sko];
    const float4 a1 = *(const float4*)&A[(size_t)(m0+srow)*512 + k0 + sko + 8];
    const float4 b0 = *(const float4*)&Bw[(size_t)(n0+srow)*512 + k0 + sko];
    const float4 b1 = *(const float4*)&Bw[(size_t)(n0+srow)*512 + k0 + sko + 8];
    *(float4*)&la[srow*40 + sko]     = a0;
    *(float4*)&la[srow*40 + sko + 8] = a1;
    *(float4*)&lb[srow*40 + sko]     = b0;
    *(float4*)&lb[srow*40 + sko + 8] = b1;
    __syncthreads();
    s16x8 af[4], bfr[4];
    #pragma unroll
    for (int mi=0; mi<4; ++mi) af[mi] = *(const s16x8*)&la[(wr*64+mi*16+fr)*40 + fq*8];
    #pragma unroll
    for (int ni=0; ni<4; ++ni) bfr[ni] = *(const s16x8*)&lb[(wc*64+ni*16+fr)*40 + fq*8];
    #pragma unroll
    for (int mi=0; mi<4; ++mi){
      #pragma unroll
      for (int ni=0; ni<4; ++ni){
        acc[mi][ni] = __builtin_amdgcn_mfma_f32_16x16x32_bf16(af[mi], bfr[ni], acc[mi][ni], 0, 0, 0);
      }
    }
    __syncthreads();
  }
  #pragma unroll
  for (int ni=0; ni<4; ++ni){
    const int n = n0 + wc*64 + ni*16 + fr;         // gate-row index: dir*1024 + g*256 + u
    const float bv = (n < 1024) ? bias_f[n] : bias_b[n-1024];
    const int dir = n >> 10, g = (n >> 8) & 3, u = n & 255;
    const int col = dir*1024 + u*4 + g;            // remapped column
    #pragma unroll
    for (int mi=0; mi<4; ++mi){
      const int mb = m0 + wr*64 + mi*16 + fq*4;
      #pragma unroll
      for (int j=0; j<4; ++j)
        pre[(size_t)(mb+j)*2048 + col] = __float2half(acc[mi][ni][j] + bv);
    }
  }
}

// ---------- recurrent LSTM: one block per (batch,dir) chain; i8 W_hh in VGPR/AGPR ----------
// grid = 32: blockIdx = b*2 + dir. 512 threads = 8 waves; wave wv owns units [wv*32, wv*32+32).
// Round-4 register envelope (the only proven no-spill config: 2 waves/SIMD, 256-reg budget).
// Deltas vs round 4: no pls LDS staging (direct per-lane uint2 pv w/ 1-step reg double-buffer),
// hoisted incrementing pre/outh pointers, f16 outh.
__global__ __launch_bounds__(512, 2) void k_recur10(
    const signed char* __restrict__ W8,
    const __half* __restrict__ pre, const int* __restrict__ doc,
    __half* __restrict__ outh)
{
  const int b = blockIdx.x >> 1, dir = blockIdx.x & 1;
  const int tid = threadIdx.x, lane = tid & 63, wv = tid >> 6;
  const int L = doc[b];

  __shared__ __align__(16) signed char hq[2][256];   // i8 h, double-buffered

  if (tid < 128) ((unsigned*)hq)[tid] = 0u;          // h_{-1} = 0

  // W_hh i8 B-fragments: lane holds W[row=g*256+wv*32+nt*16+(lane&15)][kt*64+(lane>>4)*16 ..+16]
  i32x4 wfrag[2][4][4];
  #pragma unroll
  for (int nt = 0; nt < 2; ++nt)
    #pragma unroll
    for (int g = 0; g < 4; ++g){
      const int row = g*256 + wv*32 + nt*16 + (lane & 15);
      #pragma unroll
      for (int kt = 0; kt < 4; ++kt)
        wfrag[nt][g][kt] = *(const i32x4*)&W8[(size_t)dir*262144 + (size_t)row*256 + kt*64 + (lane>>4)*16];
    }

  const int u = wv*32 + (lane & 31);     // unit owned in gate phase (lanes 0..31)
  const int pos0 = dir ? (L-1) : 0;
  // hoisted per-lane pointers, advanced by a constant each step
  const __half* pp = pre + ((size_t)(b*S_ + pos0))*2048 + dir*1024 + u*4;
  __half*       op = outh + ((size_t)(b*S_ + pos0))*512 + dir*256 + u;
  const ptrdiff_t dp  = dir ? -2048 : 2048;   // halves per step (pre row)
  const ptrdiff_t dph = dir ? -512  : 512;    // halves per step (outh row)

  float cst = 0.f;
  uint2 pv = {0,0}, pvn = {0,0};
  if (lane < 32) pv = *(const uint2*)pp;
  BAR();

  for (int t = 0; t < L; ++t){
    // prefetch next step's pre operands (consumed after MFMA phase -> latency hidden)
    if (lane < 32 && t+1 < L) pvn = *(const uint2*)(pp + dp);
    pp += dp;

    const int rbuf = (t+1) & 1, wbuf = t & 1;

    // A-fragments: only lanes with (lane&15)==0 carry the live h row (row 0); others zero
    i32x4 af[4] = {{0,0,0,0},{0,0,0,0},{0,0,0,0},{0,0,0,0}};
    if ((lane & 15) == 0){
      #pragma unroll
      for (int kt = 0; kt < 4; ++kt)
        af[kt] = *(const i32x4*)&hq[rbuf][kt*64 + (lane >> 4)*16];
    }
    i32x4 acc[2][4] = {};
    #pragma unroll
    for (int kt = 0; kt < 4; ++kt)
      #pragma unroll
      for (int nt = 0; nt < 2; ++nt)
        #pragma unroll
        for (int g = 0; g < 4; ++g)
          acc[nt][g] = __builtin_amdgcn_mfma_i32_16x16x64_i8(af[kt], wfrag[nt][g][kt], acc[nt][g], 0, 0, 0);

    // live gates sit in lanes 0-15 (row 0); spread tile nt=1 to lanes 16-31
    int ac[4];
    #pragma unroll
    for (int g = 0; g < 4; ++g){
      const int sw = __shfl_xor(acc[1][g][0], 16);
      ac[g] = (lane < 16) ? acc[0][g][0] : sw;
    }
    float hval = 0.f;
    if (lane < 32){
      const __half2* ph = (const __half2*)&pv;
      const float2 p01 = __half22float2(ph[0]);
      const float2 p23 = __half22float2(ph[1]);
      const float gi = (float)ac[0]*INVQ + p01.x;
      const float gf = (float)ac[1]*INVQ + p01.y;
      const float gg = (float)ac[2]*INVQ + p23.x;
      const float go = (float)ac[3]*INVQ + p23.y;
      const float c = sigm(gf)*cst + sigm(gi)*tanh_fast(gg);
      cst = c;
      hval = sigm(go)*tanh_fast(c);
      *op = __float2half(hval);
    }
    op += dph;
    // quantize + pack 4 lanes -> dword, write next h buffer
    int q = (int)rintf(hval*127.0f);
    q = min(127, max(-127, q));
    unsigned v = ((unsigned)(q & 255)) << ((lane & 3)*8);
    v |= __shfl_xor(v, 1);
    v |= __shfl_xor(v, 2);
    if (lane < 32 && (lane & 3) == 0)
      *(unsigned*)&hq[wbuf][u & ~3] = v;
    pv = pvn;
    BAR();
  }
}

// ---------- logits: wave per row (outh is f16) ----------
__global__ __launch_bounds__(256) void k_logits(const __half* __restrict__ outh, const float* __restrict__ mw,
    const float* __restrict__ mb, const int* __restrict__ doc, float* __restrict__ logits){
  const int w = threadIdx.x >> 6, lane = threadIdx.x & 63;
  const int r = blockIdx.x*4 + w;
  const int b = r >> 11, s = r & 2047;
  if (s >= doc[b]){
    if (lane < 13) logits[(size_t)r*13 + lane] = mb[lane];
    return;
  }
  float xv[8];
  #pragma unroll
  for (int m=0; m<8; ++m) xv[m] = __half2float(outh[(size_t)r*512 + lane + m*64]);
  #pragma unroll
  for (int k=0; k<13; ++k){
    float p = 0.f;
    #pragma unroll
    for (int m=0; m<8; ++m) p += xv[m]*mw[k*512 + lane + m*64];
    #pragma unroll
    for (int off=32; off; off>>=1) p += __shfl_down(p, off);
    if (lane == 0) logits[(size_t)r*13 + k] = p + mb[k];
  }
}

// ---------- CRF: one wave per batch; exp-transition matvec form ----------
__global__ void k_crf(const float* __restrict__ logits, const int* __restrict__ ntag,
    const int* __restrict__ doc, const float* __restrict__ trans,
    const float* __restrict__ stt, const float* __restrict__ ent, float* __restrict__ ll){
  const int b = blockIdx.x, lane = threadIdx.x;
  const int L = doc[b];
  const float* lg = logits + (size_t)b*S_*13;
  float et[13];
  #pragma unroll
  for (int i=0; i<13; ++i) et[i] = (lane < 13) ? __expf(trans[i*13 + lane]) : 0.f;
  float alpha = (lane < 13) ? (stt[lane] + lg[lane]) : -1e30f;
  float e_nxt = (L > 1 && lane < 13) ? lg[13 + lane] : 0.f;
  for (int t=1; t<L; ++t){
    const float e = e_nxt;
    if (t+1 < L && lane < 13) e_nxt = lg[(size_t)(t+1)*13 + lane];
    float m = alpha;
    #pragma unroll
    for (int off = 1; off < 16; off <<= 1) m = fmaxf(m, __shfl_xor(m, off));
    const float a = __expf(alpha - m);
    float s = 0.f;
    #pragma unroll
    for (int i=0; i<13; ++i) s += __shfl(a, i) * et[i];
    alpha = m + __logf(s) + e;
  }
  float av = (lane < 13) ? alpha + ent[lane] : -1e30f;
  float m2 = -1e30f;
  #pragma unroll
  for (int i=0; i<13; ++i) m2 = fmaxf(m2, __shfl(av, i));
  float s2 = 0.f;
  #pragma unroll
  for (int i=0; i<13; ++i) s2 += __expf(__shfl(av, i) - m2);
  const float logz = m2 + __logf(s2);
  const int* tg = ntag + (size_t)b*S_;
  float num = 0.f;
  for (int t = lane; t < L; t += 64){
    const int cur = tg[t];
    num += lg[(size_t)t*13 + cur];
    if (t >= 1) num += trans[tg[t-1]*13 + cur];
  }
  #pragma unroll
  for (int off=32; off; off>>=1) num += __shfl_down(num, off);
  if (lane == 0){
    num += stt[tg[0]] + ent[tg[L-1]];
    ll[b] = num - logz;
  }
}

extern "C" void kernel_launch(void* const* d_in, const int* in_sizes, int n_in,
                              void* d_out, int out_size, void* d_ws, size_t ws_size,
                              hipStream_t stream){
  const float* x    = (const float*)d_in[0];
  const float* gcn  = (const float*)d_in[1];
  const int* length = (const int*)d_in[3];
  const int* tags   = (const int*)d_in[4];
  const float* wihf = (const float*)d_in[5];
  const float* whhf = (const float*)d_in[6];
  const float* bf   = (const float*)d_in[7];
  const float* wihb = (const float*)d_in[8];
  const float* whhb = (const float*)d_in[9];
  const float* bb   = (const float*)d_in[10];
  const float* mw   = (const float*)d_in[11];
  const float* mb   = (const float*)d_in[12];
  const float* trans= (const float*)d_in[13];
  const float* stt  = (const float*)d_in[14];
  const float* ent  = (const float*)d_in[15];

  char* ws = (char*)d_ws;
  ushort* nx   = (ushort*)(ws + 0);              // 33,554,432 B  new_x bf16
  __half* pre  = (__half*)(ws + 33554432);       // 134,217,728 B pre-activations f16 (remapped cols)
  __half* outh = (__half*)(ws + 167772160);      // 33,554,432 B  concat h states (f16)
  ushort* wih  = (ushort*)(ws + 234881024);      // 2,097,152 B   w_ih bf16 [2048][512]
  signed char* whh8 = (signed char*)(ws + 236978176); // 524,288 B w_hh i8 [2][1024][256]
  int*    src  = (int*)(ws + 238026752);         // 131,072 B
  int*    ntag = (int*)(ws + 238157824);         // 131,072 B
  int*    cum  = (int*)(ws + 238288896);         // 4,096 B
  int*    doc  = (int*)(ws + 238292992);         // 64 B

  float* logits  = (float*)d_out;                // 425,984 floats
  float* maskout = logits + 425984;              // 32,768 floats
  float* ll      = maskout + 32768;              // 16 floats

  hipLaunchKernelGGL(k_prep,   dim3(1),        dim3(1024), 0, stream, length, cum, doc);
  hipLaunchKernelGGL(k_cast,   dim3(6144),     dim3(256),  0, stream, wihf, wihb, whhf, whhb, wih, whh8);
  hipLaunchKernelGGL(k_srcmap, dim3(128),      dim3(256),  0, stream, length, cum, tags, src, ntag);
  hipLaunchKernelGGL(k_newx,   dim3(32768),    dim3(256),  0, stream, x, gcn, src, doc, nx, maskout);
  hipLaunchKernelGGL(k_gemm,   dim3(256, 16),  dim3(256),  0, stream, nx, wih, bf, bb, doc, pre);
  hipLaunchKernelGGL(k_recur10, dim3(32),      dim3(512),  0, stream, whh8, pre, doc, outh);
  hipLaunchKernelGGL(k_logits, dim3(8192),     dim3(256),  0, stream, outh, mw, mb, doc, logits);
  hipLaunchKernelGGL(k_crf,    dim3(16),       dim3(64),   0, stream, logits, ntag, doc, trans, stt, ent, ll);
}

// Round 11
// 1647.819 us; speedup vs baseline: 3.4509x; 1.0918x over previous
//
#include <hip/hip_runtime.h>
#include <hip/hip_fp16.h>
#include <hip/hip_bf16.h>

#define B_ 16
#define N_ 64
#define T_ 32
#define D_ 512
#define H_ 256
#define K_ 13
#define S_ 2048
#define G4_ 1024

typedef float f32x4 __attribute__((ext_vector_type(4)));
typedef short s16x8 __attribute__((ext_vector_type(8)));
typedef int   i32x4 __attribute__((ext_vector_type(4)));

#define INVQ 2.0505324e-5f   /* 1/(384*127) */

// barrier with LDS-only drain: do NOT wait vmcnt (global loads/stores stay in flight)
#define BAR() do { \
  asm volatile("s_waitcnt lgkmcnt(0)" ::: "memory"); \
  __builtin_amdgcn_s_barrier(); \
  __builtin_amdgcn_sched_barrier(0); \
} while (0)

__device__ __forceinline__ float sigm(float x){ return 1.0f/(1.0f+__expf(-x)); }
__device__ __forceinline__ float tanh_fast(float x){ return 1.0f - 2.0f/(1.0f+__expf(2.0f*x)); }

// ---------- prefix sums over segment lengths ----------
__global__ void k_prep(const int* __restrict__ length, int* __restrict__ cum, int* __restrict__ doc){
  const int b = threadIdx.x >> 6, n = threadIdx.x & 63;
  const int v = length[b*N_ + n];
  int x = v;
  #pragma unroll
  for (int d = 1; d < 64; d <<= 1){
    int y = __shfl_up(x, d);
    if (n >= d) x += y;
  }
  cum[b*N_ + n] = x - v;          // exclusive
  if (n == 63) doc[b] = x;        // doc_len
}

// ---------- cast weights: w_ih -> bf16 [2048][512]; w_hh -> i8 [dir][1024][256] ----------
__global__ __launch_bounds__(256) void k_cast(const float* __restrict__ wf, const float* __restrict__ wb,
                       const float* __restrict__ hf, const float* __restrict__ hb,
                       ushort* __restrict__ wih, signed char* __restrict__ whh8){
  const int i = blockIdx.x*256 + threadIdx.x;
  if (i < 2*G4_*D_){
    const int dir = i / (G4_*D_); const int r = i % (G4_*D_);
    const float v = dir ? wb[r] : wf[r];
    ((__hip_bfloat16*)wih)[i] = __float2bfloat16(v);
  } else {
    const int j2 = i - 2*G4_*D_;
    if (j2 < 2*G4_*H_){
      const int dir = j2 >> 18; const int r = j2 & 262143;
      const float v = (dir ? hb : hf)[r];
      int q = (int)rintf(v * 384.0f);
      whh8[j2] = (signed char)min(127, max(-127, q));
    }
  }
}

// ---------- scatter source map + packed tags ----------
__global__ __launch_bounds__(256) void k_srcmap(const int* __restrict__ length, const int* __restrict__ cum,
                         const int* __restrict__ tags, int* __restrict__ src, int* __restrict__ ntag){
  const int i = blockIdx.x*256 + threadIdx.x;            // B*N*T = 32768
  const int b = i >> 11, nt = i & 2047, n = nt >> 5, t = nt & 31;
  if (t < length[b*N_ + n]){
    const int dest = cum[b*N_ + n] + t;
    src[b*S_ + dest] = nt;
    ntag[b*S_ + dest] = tags[i];
  }
}

// ---------- build packed new_x (bf16) + mask output ----------
__global__ __launch_bounds__(256) void k_newx(const float* __restrict__ x, const float* __restrict__ gcn,
                      const int* __restrict__ src, const int* __restrict__ doc,
                      ushort* __restrict__ nx, float* __restrict__ mask_out){
  const int r = blockIdx.x; const int b = r >> 11, s = r & 2047;
  const int L = doc[b];
  const int d = threadIdx.x*2;
  const float2 g2 = *(const float2*)&gcn[((size_t)(b*N_ + (s>>5)))*D_ + d];
  float v0 = g2.x, v1 = g2.y;
  if (s < L){
    const int nt = src[r];
    const float2 x2 = *(const float2*)&x[((size_t)(b*S_ + nt))*D_ + d];
    v0 += x2.x; v1 += x2.y;
  }
  __hip_bfloat16* o = (__hip_bfloat16*)nx + (size_t)r*D_ + d;
  o[0] = __float2bfloat16(v0); o[1] = __float2bfloat16(v1);
  if (threadIdx.x == 0) mask_out[r] = (s < L) ? 1.0f : 0.0f;
}

// ---------- input projection GEMM ----------
// pre layout (REMAPPED for recur): pre[b][s][dir*1024 + u*4 + g]  (f16, bias added)
__global__ __launch_bounds__(256) void k_gemm(const ushort* __restrict__ A, const ushort* __restrict__ Bw,
    const float* __restrict__ bias_f, const float* __restrict__ bias_b,
    const int* __restrict__ doc, __half* __restrict__ pre){
  const int m0 = blockIdx.x*128, n0 = blockIdx.y*128;
  const int b = m0 >> 11, s0 = m0 & 2047;
  if (s0 >= doc[b]) return;
  __shared__ __align__(16) ushort la[128*40];
  __shared__ __align__(16) ushort lb[128*40];
  const int tid = threadIdx.x, lane = tid & 63, w = tid >> 6;
  const int wr = w >> 1, wc = w & 1;
  const int fr = lane & 15, fq = lane >> 4;
  f32x4 acc[4][4] = {};
  const int srow = tid >> 1;
  const int sko  = (tid & 1)*16;
  for (int kt = 0; kt < 16; ++kt){
    const int k0 = kt*32;
    const float4 a0 = *(const float4*)&A[(size_t)(m0+srow)*512 + k0 + sko];
    const float4 a1 = *(const float4*)&A[(size_t)(m0+srow)*512 + k0 + sko + 8];
    const float4 b0 = *(const float4*)&Bw[(size_t)(n0+srow)*512 + k0 + sko];
    const float4 b1 = *(const float4*)&Bw[(size_t)(n0+srow)*512 + k0 + sko + 8];
    *(float4*)&la[srow*40 + sko]     = a0;
    *(float4*)&la[srow*40 + sko + 8] = a1;
    *(float4*)&lb[srow*40 + sko]     = b0;
    *(float4*)&lb[srow*40 + sko + 8] = b1;
    __syncthreads();
    s16x8 af[4], bfr[4];
    #pragma unroll
    for (int mi=0; mi<4; ++mi) af[mi] = *(const s16x8*)&la[(wr*64+mi*16+fr)*40 + fq*8];
    #pragma unroll
    for (int ni=0; ni<4; ++ni) bfr[ni] = *(const s16x8*)&lb[(wc*64+ni*16+fr)*40 + fq*8];
    #pragma unroll
    for (int mi=0; mi<4; ++mi){
      #pragma unroll
      for (int ni=0; ni<4; ++ni){
        acc[mi][ni] = __builtin_amdgcn_mfma_f32_16x16x32_bf16(af[mi], bfr[ni], acc[mi][ni], 0, 0, 0);
      }
    }
    __syncthreads();
  }
  #pragma unroll
  for (int ni=0; ni<4; ++ni){
    const int n = n0 + wc*64 + ni*16 + fr;         // gate-row index: dir*1024 + g*256 + u
    const float bv = (n < 1024) ? bias_f[n] : bias_b[n-1024];
    const int dir = n >> 10, g = (n >> 8) & 3, u = n & 255;
    const int col = dir*1024 + u*4 + g;            // remapped column
    #pragma unroll
    for (int mi=0; mi<4; ++mi){
      const int mb = m0 + wr*64 + mi*16 + fq*4;
      #pragma unroll
      for (int j=0; j<4; ++j)
        pre[(size_t)(mb+j)*2048 + col] = __float2half(acc[mi][ni][j] + bv);
    }
  }
}

// ---------- recurrent LSTM: one block per (batch,dir) chain; i8 W_hh resident ----------
// grid = 32: blockIdx = b*2 + dir. 512 threads = 8 waves; wave wv owns units [wv*32, wv*32+32).
// BROADCAST-A: every lane loads the same h chunk (row-agnostic) -> all 16 C rows identical ->
// no af zeroing, no lane masks on MFMA input, no shfl redistribution (a[0] has the answer in
// every lane; lanes 16-31 just select the nt=1 group). Chained accumulate with loop-invariant
// zero C kills per-step acc init. Direct ds_write_b8 for h (h in (-1,1) -> clamp-free quant).
__global__ __launch_bounds__(512, 2) void k_recur11(
    const signed char* __restrict__ W8,
    const __half* __restrict__ pre, const int* __restrict__ doc,
    __half* __restrict__ outh)
{
  const int b = blockIdx.x >> 1, dir = blockIdx.x & 1;
  const int tid = threadIdx.x, lane = tid & 63, wv = tid >> 6;
  const int L = doc[b];

  __shared__ __align__(16) signed char hq[2][256];   // i8 h, double-buffered

  if (tid < 128) ((unsigned*)hq)[tid] = 0u;          // h_{-1} = 0

  // W_hh i8 B-fragments: lane holds W[row=g*256+wv*32+nt*16+(lane&15)][kt*64+(lane>>4)*16 ..+16]
  i32x4 wfrag[2][4][4];
  #pragma unroll
  for (int nt = 0; nt < 2; ++nt)
    #pragma unroll
    for (int g = 0; g < 4; ++g){
      const int row = g*256 + wv*32 + nt*16 + (lane & 15);
      #pragma unroll
      for (int kt = 0; kt < 4; ++kt)
        wfrag[nt][g][kt] = *(const i32x4*)&W8[(size_t)dir*262144 + (size_t)row*256 + kt*64 + (lane>>4)*16];
    }

  const int u = wv*32 + (lane & 31);     // unit owned in gate phase (lanes 32-63 mirror 0-31)
  const int koff = (lane >> 4)*16;       // 16-byte k-chunk this lane supplies to the A-frag
  const int pos0 = dir ? (L-1) : 0;
  const __half* pp = pre + ((size_t)(b*S_ + pos0))*2048 + dir*1024 + u*4;
  __half*       op = outh + ((size_t)(b*S_ + pos0))*512 + dir*256 + u;
  const ptrdiff_t dp  = dir ? -2048 : 2048;   // halves per step (pre row)
  const ptrdiff_t dph = dir ? -512  : 512;    // halves per step (outh row)

  float cst = 0.f;
  uint2 pv, pvn = {0,0};
  pv = *(const uint2*)pp;                // lanes 32-63 load valid duplicates of lanes 0-31
  const i32x4 z = {0,0,0,0};
  BAR();

  for (int t = 0; t < L; ++t){
    // prefetch next step's pre operands (consumed after MFMA phase -> latency hidden)
    if (t+1 < L) pvn = *(const uint2*)(pp + dp);
    pp += dp;

    const int rbuf = (t+1) & 1, wbuf = t & 1;

    // broadcast A-fragments: uniform per 16-lane group -> LDS broadcast, conflict-free
    i32x4 af[4];
    #pragma unroll
    for (int kt = 0; kt < 4; ++kt)
      af[kt] = *(const i32x4*)&hq[rbuf][kt*64 + koff];

    // grouped chained accumulate; every C row identical so element 0 is the gate sum
    int g2[2][4];
    #pragma unroll
    for (int nt = 0; nt < 2; ++nt)
      #pragma unroll
      for (int g = 0; g < 4; ++g){
        i32x4 a = __builtin_amdgcn_mfma_i32_16x16x64_i8(af[0], wfrag[nt][g][0], z, 0, 0, 0);
        a = __builtin_amdgcn_mfma_i32_16x16x64_i8(af[1], wfrag[nt][g][1], a, 0, 0, 0);
        a = __builtin_amdgcn_mfma_i32_16x16x64_i8(af[2], wfrag[nt][g][2], a, 0, 0, 0);
        a = __builtin_amdgcn_mfma_i32_16x16x64_i8(af[3], wfrag[nt][g][3], a, 0, 0, 0);
        g2[nt][g] = a[0];
      }

    // lanes 0-15 own nt=0 units, 16-31 own nt=1 units (32-63 compute mirrored values, unused)
    const bool hi = (lane & 16) != 0;
    const __half2* ph = (const __half2*)&pv;
    const float2 p01 = __half22float2(ph[0]);
    const float2 p23 = __half22float2(ph[1]);
    const float gi = (float)(hi ? g2[1][0] : g2[0][0])*INVQ + p01.x;
    const float gf = (float)(hi ? g2[1][1] : g2[0][1])*INVQ + p01.y;
    const float gg = (float)(hi ? g2[1][2] : g2[0][2])*INVQ + p23.x;
    const float go = (float)(hi ? g2[1][3] : g2[0][3])*INVQ + p23.y;
    const float c = sigm(gf)*cst + sigm(gi)*tanh_fast(gg);
    cst = c;
    const float hval = sigm(go)*tanh_fast(c);
    if (lane < 32){
      *op = __float2half(hval);
      hq[wbuf][u] = (signed char)(int)rintf(hval*127.0f);  // h in (-1,1): no clamp needed
    }
    op += dph;
    pv = pvn;
    BAR();
  }
}

// ---------- logits: wave per row (outh is f16) ----------
__global__ __launch_bounds__(256) void k_logits(const __half* __restrict__ outh, const float* __restrict__ mw,
    const float* __restrict__ mb, const int* __restrict__ doc, float* __restrict__ logits){
  const int w = threadIdx.x >> 6, lane = threadIdx.x & 63;
  const int r = blockIdx.x*4 + w;
  const int b = r >> 11, s = r & 2047;
  if (s >= doc[b]){
    if (lane < 13) logits[(size_t)r*13 + lane] = mb[lane];
    return;
  }
  float xv[8];
  #pragma unroll
  for (int m=0; m<8; ++m) xv[m] = __half2float(outh[(size_t)r*512 + lane + m*64]);
  #pragma unroll
  for (int k=0; k<13; ++k){
    float p = 0.f;
    #pragma unroll
    for (int m=0; m<8; ++m) p += xv[m]*mw[k*512 + lane + m*64];
    #pragma unroll
    for (int off=32; off; off>>=1) p += __shfl_down(p, off);
    if (lane == 0) logits[(size_t)r*13 + k] = p + mb[k];
  }
}

// ---------- CRF: one wave per batch; exp-transition matvec form ----------
__global__ void k_crf(const float* __restrict__ logits, const int* __restrict__ ntag,
    const int* __restrict__ doc, const float* __restrict__ trans,
    const float* __restrict__ stt, const float* __restrict__ ent, float* __restrict__ ll){
  const int b = blockIdx.x, lane = threadIdx.x;
  const int L = doc[b];
  const float* lg = logits + (size_t)b*S_*13;
  float et[13];
  #pragma unroll
  for (int i=0; i<13; ++i) et[i] = (lane < 13) ? __expf(trans[i*13 + lane]) : 0.f;
  float alpha = (lane < 13) ? (stt[lane] + lg[lane]) : -1e30f;
  float e_nxt = (L > 1 && lane < 13) ? lg[13 + lane] : 0.f;
  for (int t=1; t<L; ++t){
    const float e = e_nxt;
    if (t+1 < L && lane < 13) e_nxt = lg[(size_t)(t+1)*13 + lane];
    float m = alpha;
    #pragma unroll
    for (int off = 1; off < 16; off <<= 1) m = fmaxf(m, __shfl_xor(m, off));
    const float a = __expf(alpha - m);
    float s = 0.f;
    #pragma unroll
    for (int i=0; i<13; ++i) s += __shfl(a, i) * et[i];
    alpha = m + __logf(s) + e;
  }
  float av = (lane < 13) ? alpha + ent[lane] : -1e30f;
  float m2 = -1e30f;
  #pragma unroll
  for (int i=0; i<13; ++i) m2 = fmaxf(m2, __shfl(av, i));
  float s2 = 0.f;
  #pragma unroll
  for (int i=0; i<13; ++i) s2 += __expf(__shfl(av, i) - m2);
  const float logz = m2 + __logf(s2);
  const int* tg = ntag + (size_t)b*S_;
  float num = 0.f;
  for (int t = lane; t < L; t += 64){
    const int cur = tg[t];
    num += lg[(size_t)t*13 + cur];
    if (t >= 1) num += trans[tg[t-1]*13 + cur];
  }
  #pragma unroll
  for (int off=32; off; off>>=1) num += __shfl_down(num, off);
  if (lane == 0){
    num += stt[tg[0]] + ent[tg[L-1]];
    ll[b] = num - logz;
  }
}

extern "C" void kernel_launch(void* const* d_in, const int* in_sizes, int n_in,
                              void* d_out, int out_size, void* d_ws, size_t ws_size,
                              hipStream_t stream){
  const float* x    = (const float*)d_in[0];
  const float* gcn  = (const float*)d_in[1];
  const int* length = (const int*)d_in[3];
  const int* tags   = (const int*)d_in[4];
  const float* wihf = (const float*)d_in[5];
  const float* whhf = (const float*)d_in[6];
  const float* bf   = (const float*)d_in[7];
  const float* wihb = (const float*)d_in[8];
  const float* whhb = (const float*)d_in[9];
  const float* bb   = (const float*)d_in[10];
  const float* mw   = (const float*)d_in[11];
  const float* mb   = (const float*)d_in[12];
  const float* trans= (const float*)d_in[13];
  const float* stt  = (const float*)d_in[14];
  const float* ent  = (const float*)d_in[15];

  char* ws = (char*)d_ws;
  ushort* nx   = (ushort*)(ws + 0);              // 33,554,432 B  new_x bf16
  __half* pre  = (__half*)(ws + 33554432);       // 134,217,728 B pre-activations f16 (remapped cols)
  __half* outh = (__half*)(ws + 167772160);      // 33,554,432 B  concat h states (f16)
  ushort* wih  = (ushort*)(ws + 234881024);      // 2,097,152 B   w_ih bf16 [2048][512]
  signed char* whh8 = (signed char*)(ws + 236978176); // 524,288 B w_hh i8 [2][1024][256]
  int*    src  = (int*)(ws + 238026752);         // 131,072 B
  int*    ntag = (int*)(ws + 238157824);         // 131,072 B
  int*    cum  = (int*)(ws + 238288896);         // 4,096 B
  int*    doc  = (int*)(ws + 238292992);         // 64 B

  float* logits  = (float*)d_out;                // 425,984 floats
  float* maskout = logits + 425984;              // 32,768 floats
  float* ll      = maskout + 32768;              // 16 floats

  hipLaunchKernelGGL(k_prep,   dim3(1),        dim3(1024), 0, stream, length, cum, doc);
  hipLaunchKernelGGL(k_cast,   dim3(6144),     dim3(256),  0, stream, wihf, wihb, whhf, whhb, wih, whh8);
  hipLaunchKernelGGL(k_srcmap, dim3(128),      dim3(256),  0, stream, length, cum, tags, src, ntag);
  hipLaunchKernelGGL(k_newx,   dim3(32768),    dim3(256),  0, stream, x, gcn, src, doc, nx, maskout);
  hipLaunchKernelGGL(k_gemm,   dim3(256, 16),  dim3(256),  0, stream, nx, wih, bf, bb, doc, pre);
  hipLaunchKernelGGL(k_recur11, dim3(32),      dim3(512),  0, stream, whh8, pre, doc, outh);
  hipLaunchKernelGGL(k_logits, dim3(8192),     dim3(256),  0, stream, outh, mw, mb, doc, logits);
  hipLaunchKernelGGL(k_crf,    dim3(16),       dim3(64),   0, stream, logits, ntag, doc, trans, stt, ent, ll);
}

// Round 12
// 1535.026 us; speedup vs baseline: 3.7045x; 1.0735x over previous
//
#include <hip/hip_runtime.h>
#include <hip/hip_fp16.h>
#include <hip/hip_bf16.h>

#define B_ 16
#define N_ 64
#define T_ 32
#define D_ 512
#define H_ 256
#define K_ 13
#define S_ 2048
#define G4_ 1024

typedef float f32x4 __attribute__((ext_vector_type(4)));
typedef short s16x8 __attribute__((ext_vector_type(8)));
typedef int   i32x4 __attribute__((ext_vector_type(4)));

#define LOG2E 1.44269504f
#define INVQ  2.0505324e-5f    /* 1/(384*127) */
#define INVQ2 2.9582873e-5f    /* INVQ * log2e */

// barrier with LDS-only drain: do NOT wait vmcnt (global loads/stores stay in flight)
#define BAR() do { \
  asm volatile("s_waitcnt lgkmcnt(0)" ::: "memory"); \
  __builtin_amdgcn_s_barrier(); \
  __builtin_amdgcn_sched_barrier(0); \
} while (0)

__device__ __forceinline__ float sigm(float x){ return 1.0f/(1.0f+__expf(-x)); }
__device__ __forceinline__ float tanh_fast(float x){ return 1.0f - 2.0f/(1.0f+__expf(2.0f*x)); }

// log2e-unit variants: y = x*log2e; v_exp_f32 is natively 2^x, v_rcp via builtin (fast, 1ulp)
__device__ __forceinline__ float sigm2(float y){ return __builtin_amdgcn_rcpf(1.0f + exp2f(-y)); }
__device__ __forceinline__ float tanh2(float y){ return 1.0f - 2.0f*__builtin_amdgcn_rcpf(1.0f + exp2f(2.0f*y)); }

// ---------- prefix sums over segment lengths ----------
__global__ void k_prep(const int* __restrict__ length, int* __restrict__ cum, int* __restrict__ doc){
  const int b = threadIdx.x >> 6, n = threadIdx.x & 63;
  const int v = length[b*N_ + n];
  int x = v;
  #pragma unroll
  for (int d = 1; d < 64; d <<= 1){
    int y = __shfl_up(x, d);
    if (n >= d) x += y;
  }
  cum[b*N_ + n] = x - v;          // exclusive
  if (n == 63) doc[b] = x;        // doc_len
}

// ---------- cast weights: w_ih -> bf16 [2048][512]; w_hh -> i8 [dir][1024][256] ----------
__global__ __launch_bounds__(256) void k_cast(const float* __restrict__ wf, const float* __restrict__ wb,
                       const float* __restrict__ hf, const float* __restrict__ hb,
                       ushort* __restrict__ wih, signed char* __restrict__ whh8){
  const int i = blockIdx.x*256 + threadIdx.x;
  if (i < 2*G4_*D_){
    const int dir = i / (G4_*D_); const int r = i % (G4_*D_);
    const float v = dir ? wb[r] : wf[r];
    ((__hip_bfloat16*)wih)[i] = __float2bfloat16(v);
  } else {
    const int j2 = i - 2*G4_*D_;
    if (j2 < 2*G4_*H_){
      const int dir = j2 >> 18; const int r = j2 & 262143;
      const float v = (dir ? hb : hf)[r];
      int q = (int)rintf(v * 384.0f);
      whh8[j2] = (signed char)min(127, max(-127, q));
    }
  }
}

// ---------- scatter source map + packed tags ----------
__global__ __launch_bounds__(256) void k_srcmap(const int* __restrict__ length, const int* __restrict__ cum,
                         const int* __restrict__ tags, int* __restrict__ src, int* __restrict__ ntag){
  const int i = blockIdx.x*256 + threadIdx.x;            // B*N*T = 32768
  const int b = i >> 11, nt = i & 2047, n = nt >> 5, t = nt & 31;
  if (t < length[b*N_ + n]){
    const int dest = cum[b*N_ + n] + t;
    src[b*S_ + dest] = nt;
    ntag[b*S_ + dest] = tags[i];
  }
}

// ---------- build packed new_x (bf16) + mask output ----------
__global__ __launch_bounds__(256) void k_newx(const float* __restrict__ x, const float* __restrict__ gcn,
                      const int* __restrict__ src, const int* __restrict__ doc,
                      ushort* __restrict__ nx, float* __restrict__ mask_out){
  const int r = blockIdx.x; const int b = r >> 11, s = r & 2047;
  const int L = doc[b];
  const int d = threadIdx.x*2;
  const float2 g2 = *(const float2*)&gcn[((size_t)(b*N_ + (s>>5)))*D_ + d];
  float v0 = g2.x, v1 = g2.y;
  if (s < L){
    const int nt = src[r];
    const float2 x2 = *(const float2*)&x[((size_t)(b*S_ + nt))*D_ + d];
    v0 += x2.x; v1 += x2.y;
  }
  __hip_bfloat16* o = (__hip_bfloat16*)nx + (size_t)r*D_ + d;
  o[0] = __float2bfloat16(v0); o[1] = __float2bfloat16(v1);
  if (threadIdx.x == 0) mask_out[r] = (s < L) ? 1.0f : 0.0f;
}

// ---------- input projection GEMM ----------
// pre layout (REMAPPED for recur): pre[b][s][dir*1024 + u*4 + g]  (f16, bias added,
// PRE-SCALED by log2e so the recurrence's exp() becomes native exp2)
__global__ __launch_bounds__(256) void k_gemm(const ushort* __restrict__ A, const ushort* __restrict__ Bw,
    const float* __restrict__ bias_f, const float* __restrict__ bias_b,
    const int* __restrict__ doc, __half* __restrict__ pre){
  const int m0 = blockIdx.x*128, n0 = blockIdx.y*128;
  const int b = m0 >> 11, s0 = m0 & 2047;
  if (s0 >= doc[b]) return;
  __shared__ __align__(16) ushort la[128*40];
  __shared__ __align__(16) ushort lb[128*40];
  const int tid = threadIdx.x, lane = tid & 63, w = tid >> 6;
  const int wr = w >> 1, wc = w & 1;
  const int fr = lane & 15, fq = lane >> 4;
  f32x4 acc[4][4] = {};
  const int srow = tid >> 1;
  const int sko  = (tid & 1)*16;
  for (int kt = 0; kt < 16; ++kt){
    const int k0 = kt*32;
    const float4 a0 = *(const float4*)&A[(size_t)(m0+srow)*512 + k0 + sko];
    const float4 a1 = *(const float4*)&A[(size_t)(m0+srow)*512 + k0 + sko + 8];
    const float4 b0 = *(const float4*)&Bw[(size_t)(n0+srow)*512 + k0 + sko];
    const float4 b1 = *(const float4*)&Bw[(size_t)(n0+srow)*512 + k0 + sko + 8];
    *(float4*)&la[srow*40 + sko]     = a0;
    *(float4*)&la[srow*40 + sko + 8] = a1;
    *(float4*)&lb[srow*40 + sko]     = b0;
    *(float4*)&lb[srow*40 + sko + 8] = b1;
    __syncthreads();
    s16x8 af[4], bfr[4];
    #pragma unroll
    for (int mi=0; mi<4; ++mi) af[mi] = *(const s16x8*)&la[(wr*64+mi*16+fr)*40 + fq*8];
    #pragma unroll
    for (int ni=0; ni<4; ++ni) bfr[ni] = *(const s16x8*)&lb[(wc*64+ni*16+fr)*40 + fq*8];
    #pragma unroll
    for (int mi=0; mi<4; ++mi){
      #pragma unroll
      for (int ni=0; ni<4; ++ni){
        acc[mi][ni] = __builtin_amdgcn_mfma_f32_16x16x32_bf16(af[mi], bfr[ni], acc[mi][ni], 0, 0, 0);
      }
    }
    __syncthreads();
  }
  #pragma unroll
  for (int ni=0; ni<4; ++ni){
    const int n = n0 + wc*64 + ni*16 + fr;         // gate-row index: dir*1024 + g*256 + u
    const float bv = (n < 1024) ? bias_f[n] : bias_b[n-1024];
    const int dir = n >> 10, g = (n >> 8) & 3, u = n & 255;
    const int col = dir*1024 + u*4 + g;            // remapped column
    #pragma unroll
    for (int mi=0; mi<4; ++mi){
      const int mb = m0 + wr*64 + mi*16 + fq*4;
      #pragma unroll
      for (int j=0; j<4; ++j)
        pre[(size_t)(mb+j)*2048 + col] = __float2half((acc[mi][ni][j] + bv)*LOG2E);
    }
  }
}

// ---------- recurrent LSTM: one block per (batch,dir) chain; i8 W_hh in AGPRs ----------
// grid = 32: blockIdx = b*2 + dir. 512 threads = 8 waves; wave wv owns units [wv*32, wv*32+32).
// Broadcast-A (all C rows identical); g-major chained MFMAs so the c-chain VALU runs under
// the o-gate's MFMAs; native exp2 + v_rcp gates (pre is pre-scaled by log2e in k_gemm).
__global__ __launch_bounds__(512, 2) void k_recur12(
    const signed char* __restrict__ W8,
    const __half* __restrict__ pre, const int* __restrict__ doc,
    __half* __restrict__ outh)
{
  const int b = blockIdx.x >> 1, dir = blockIdx.x & 1;
  const int tid = threadIdx.x, lane = tid & 63, wv = tid >> 6;
  const int L = doc[b];

  __shared__ __align__(16) signed char hq[2][256];   // i8 h, double-buffered

  if (tid < 128) ((unsigned*)hq)[tid] = 0u;          // h_{-1} = 0

  // W_hh i8 B-fragments: lane holds W[row=g*256+wv*32+nt*16+(lane&15)][kt*64+(lane>>4)*16 ..+16]
  i32x4 wfrag[2][4][4];
  #pragma unroll
  for (int nt = 0; nt < 2; ++nt)
    #pragma unroll
    for (int g = 0; g < 4; ++g){
      const int row = g*256 + wv*32 + nt*16 + (lane & 15);
      #pragma unroll
      for (int kt = 0; kt < 4; ++kt)
        wfrag[nt][g][kt] = *(const i32x4*)&W8[(size_t)dir*262144 + (size_t)row*256 + kt*64 + (lane>>4)*16];
    }

  const int u = wv*32 + (lane & 31);     // unit owned in gate phase (lanes 32-63 mirror 0-31)
  const int koff = (lane >> 4)*16;       // 16-byte k-chunk this lane supplies to the A-frag
  const int pos0 = dir ? (L-1) : 0;
  const __half* pp = pre + ((size_t)(b*S_ + pos0))*2048 + dir*1024 + u*4;
  __half*       op = outh + ((size_t)(b*S_ + pos0))*512 + dir*256 + u;
  const ptrdiff_t dp  = dir ? -2048 : 2048;   // halves per step (pre row)
  const ptrdiff_t dph = dir ? -512  : 512;    // halves per step (outh row)

  float cst = 0.f;
  uint2 pv, pvn = {0,0};
  pv = *(const uint2*)pp;                // lanes 32-63 load valid duplicates of lanes 0-31
  const i32x4 z = {0,0,0,0};
  BAR();

  for (int t = 0; t < L; ++t){
    // prefetch next step's pre operands (consumed after MFMA phase -> latency hidden)
    if (t+1 < L) pvn = *(const uint2*)(pp + dp);
    pp += dp;

    const int rbuf = (t+1) & 1, wbuf = t & 1;

    // broadcast A-fragments: uniform per 16-lane group -> LDS broadcast, conflict-free
    i32x4 af[4];
    #pragma unroll
    for (int kt = 0; kt < 4; ++kt)
      af[kt] = *(const i32x4*)&hq[rbuf][kt*64 + koff];

    // chained K-accumulate for one (nt, gate); all C rows identical -> a[0] is the gate sum
    auto chain4 = [&](const i32x4* w4) -> int {
      i32x4 a = __builtin_amdgcn_mfma_i32_16x16x64_i8(af[0], w4[0], z, 0, 0, 0);
      a = __builtin_amdgcn_mfma_i32_16x16x64_i8(af[1], w4[1], a, 0, 0, 0);
      a = __builtin_amdgcn_mfma_i32_16x16x64_i8(af[2], w4[2], a, 0, 0, 0);
      a = __builtin_amdgcn_mfma_i32_16x16x64_i8(af[3], w4[3], a, 0, 0, 0);
      return a[0];
    };

    const bool hi = (lane & 16) != 0;
    const __half2* ph = (const __half2*)&pv;
    const float2 p01 = __half22float2(ph[0]);
    const float2 p23 = __half22float2(ph[1]);

    // gates i,f,g first; c-chain VALU overlaps the o-gate MFMAs below
    const int i0 = chain4(wfrag[0][0]), i1 = chain4(wfrag[1][0]);
    const int f0 = chain4(wfrag[0][1]), f1 = chain4(wfrag[1][1]);
    const int q0 = chain4(wfrag[0][2]), q1 = chain4(wfrag[1][2]);
    const float giy = (float)(hi ? i1 : i0)*INVQ2 + p01.x;
    const float gfy = (float)(hi ? f1 : f0)*INVQ2 + p01.y;
    const float ggy = (float)(hi ? q1 : q0)*INVQ2 + p23.x;
    const int o0 = chain4(wfrag[0][3]), o1 = chain4(wfrag[1][3]);
    const float c = sigm2(gfy)*cst + sigm2(giy)*tanh2(ggy);
    cst = c;
    const float goy = (float)(hi ? o1 : o0)*INVQ2 + p23.y;
    const float hval = sigm2(goy)*tanh2(c*LOG2E);

    if (lane < 32){
      *op = __float2half(hval);
      hq[wbuf][u] = (signed char)(int)rintf(hval*127.0f);  // h in (-1,1): no clamp needed
    }
    op += dph;
    pv = pvn;
    BAR();
  }
}

// ---------- logits: wave per row (outh is f16) ----------
__global__ __launch_bounds__(256) void k_logits(const __half* __restrict__ outh, const float* __restrict__ mw,
    const float* __restrict__ mb, const int* __restrict__ doc, float* __restrict__ logits){
  const int w = threadIdx.x >> 6, lane = threadIdx.x & 63;
  const int r = blockIdx.x*4 + w;
  const int b = r >> 11, s = r & 2047;
  if (s >= doc[b]){
    if (lane < 13) logits[(size_t)r*13 + lane] = mb[lane];
    return;
  }
  float xv[8];
  #pragma unroll
  for (int m=0; m<8; ++m) xv[m] = __half2float(outh[(size_t)r*512 + lane + m*64]);
  #pragma unroll
  for (int k=0; k<13; ++k){
    float p = 0.f;
    #pragma unroll
    for (int m=0; m<8; ++m) p += xv[m]*mw[k*512 + lane + m*64];
    #pragma unroll
    for (int off=32; off; off>>=1) p += __shfl_down(p, off);
    if (lane == 0) logits[(size_t)r*13 + k] = p + mb[k];
  }
}

// ---------- CRF: one wave per batch; exp-transition matvec form ----------
__global__ void k_crf(const float* __restrict__ logits, const int* __restrict__ ntag,
    const int* __restrict__ doc, const float* __restrict__ trans,
    const float* __restrict__ stt, const float* __restrict__ ent, float* __restrict__ ll){
  const int b = blockIdx.x, lane = threadIdx.x;
  const int L = doc[b];
  const float* lg = logits + (size_t)b*S_*13;
  float et[13];
  #pragma unroll
  for (int i=0; i<13; ++i) et[i] = (lane < 13) ? __expf(trans[i*13 + lane]) : 0.f;
  float alpha = (lane < 13) ? (stt[lane] + lg[lane]) : -1e30f;
  float e_nxt = (L > 1 && lane < 13) ? lg[13 + lane] : 0.f;
  for (int t=1; t<L; ++t){
    const float e = e_nxt;
    if (t+1 < L && lane < 13) e_nxt = lg[(size_t)(t+1)*13 + lane];
    float m = alpha;
    #pragma unroll
    for (int off = 1; off < 16; off <<= 1) m = fmaxf(m, __shfl_xor(m, off));
    const float a = __expf(alpha - m);
    float s = 0.f;
    #pragma unroll
    for (int i=0; i<13; ++i) s += __shfl(a, i) * et[i];
    alpha = m + __logf(s) + e;
  }
  float av = (lane < 13) ? alpha + ent[lane] : -1e30f;
  float m2 = -1e30f;
  #pragma unroll
  for (int i=0; i<13; ++i) m2 = fmaxf(m2, __shfl(av, i));
  float s2 = 0.f;
  #pragma unroll
  for (int i=0; i<13; ++i) s2 += __expf(__shfl(av, i) - m2);
  const float logz = m2 + __logf(s2);
  const int* tg = ntag + (size_t)b*S_;
  float num = 0.f;
  for (int t = lane; t < L; t += 64){
    const int cur = tg[t];
    num += lg[(size_t)t*13 + cur];
    if (t >= 1) num += trans[tg[t-1]*13 + cur];
  }
  #pragma unroll
  for (int off=32; off; off>>=1) num += __shfl_down(num, off);
  if (lane == 0){
    num += stt[tg[0]] + ent[tg[L-1]];
    ll[b] = num - logz;
  }
}

extern "C" void kernel_launch(void* const* d_in, const int* in_sizes, int n_in,
                              void* d_out, int out_size, void* d_ws, size_t ws_size,
                              hipStream_t stream){
  const float* x    = (const float*)d_in[0];
  const float* gcn  = (const float*)d_in[1];
  const int* length = (const int*)d_in[3];
  const int* tags   = (const int*)d_in[4];
  const float* wihf = (const float*)d_in[5];
  const float* whhf = (const float*)d_in[6];
  const float* bf   = (const float*)d_in[7];
  const float* wihb = (const float*)d_in[8];
  const float* whhb = (const float*)d_in[9];
  const float* bb   = (const float*)d_in[10];
  const float* mw   = (const float*)d_in[11];
  const float* mb   = (const float*)d_in[12];
  const float* trans= (const float*)d_in[13];
  const float* stt  = (const float*)d_in[14];
  const float* ent  = (const float*)d_in[15];

  char* ws = (char*)d_ws;
  ushort* nx   = (ushort*)(ws + 0);              // 33,554,432 B  new_x bf16
  __half* pre  = (__half*)(ws + 33554432);       // 134,217,728 B pre-activations f16 (remapped, log2e-scaled)
  __half* outh = (__half*)(ws + 167772160);      // 33,554,432 B  concat h states (f16)
  ushort* wih  = (ushort*)(ws + 234881024);      // 2,097,152 B   w_ih bf16 [2048][512]
  signed char* whh8 = (signed char*)(ws + 236978176); // 524,288 B w_hh i8 [2][1024][256]
  int*    src  = (int*)(ws + 238026752);         // 131,072 B
  int*    ntag = (int*)(ws + 238157824);         // 131,072 B
  int*    cum  = (int*)(ws + 238288896);         // 4,096 B
  int*    doc  = (int*)(ws + 238292992);         // 64 B

  float* logits  = (float*)d_out;                // 425,984 floats
  float* maskout = logits + 425984;              // 32,768 floats
  float* ll      = maskout + 32768;              // 16 floats

  hipLaunchKernelGGL(k_prep,   dim3(1),        dim3(1024), 0, stream, length, cum, doc);
  hipLaunchKernelGGL(k_cast,   dim3(6144),     dim3(256),  0, stream, wihf, wihb, whhf, whhb, wih, whh8);
  hipLaunchKernelGGL(k_srcmap, dim3(128),      dim3(256),  0, stream, length, cum, tags, src, ntag);
  hipLaunchKernelGGL(k_newx,   dim3(32768),    dim3(256),  0, stream, x, gcn, src, doc, nx, maskout);
  hipLaunchKernelGGL(k_gemm,   dim3(256, 16),  dim3(256),  0, stream, nx, wih, bf, bb, doc, pre);
  hipLaunchKernelGGL(k_recur12, dim3(32),      dim3(512),  0, stream, whh8, pre, doc, outh);
  hipLaunchKernelGGL(k_logits, dim3(8192),     dim3(256),  0, stream, outh, mw, mb, doc, logits);
  hipLaunchKernelGGL(k_crf,    dim3(16),       dim3(64),   0, stream, logits, ntag, doc, trans, stt, ent, ll);
}